// Round 6
// baseline (192.142 us; speedup 1.0000x reference)
//
#include <hip/hip_runtime.h>
#include <hip/hip_fp16.h>
#include <math.h>

#define LN_ZERO (-100000000000.0f)

constexpr int F_ = 250000;
constexpr int V_ = 250000;
constexpr int E_ = 1000000;      // F_ * 4
constexpr int SCAN_B = 1024;
constexpr int NB_SCAN = (V_ + SCAN_B - 1) / SCAN_B;   // 245
static_assert(NB_SCAN <= 256, "top-level scan assumes <=256 partials");

// Partitioned counting-sort parameters
constexpr int PARTS  = 16;
constexpr int SLICES = 8;
constexpr int BINS    = V_ / PARTS;    // 15625 (exact)
constexpr int SLICE_E = E_ / SLICES;   // 125000 (exact)
static_assert(PARTS * BINS == V_, "");
static_assert(SLICES * SLICE_E == E_, "");

// ---------------------------------------------------------------------------
// Prep: compress potmask [F,16] int32 -> ushort bitmask per factor.
__global__ void k_prep(const int4* __restrict__ potmask4,
                       unsigned short* __restrict__ potbits) {
    int f = blockIdx.x * blockDim.x + threadIdx.x;
    if (f >= F_) return;
    unsigned int bits = 0;
#pragma unroll
    for (int j = 0; j < 4; ++j) {
        int4 pm = potmask4[4 * f + j];
        bits |= (pm.x == 1 ? 1u : 0u) << (4 * j + 0);
        bits |= (pm.y == 1 ? 1u : 0u) << (4 * j + 1);
        bits |= (pm.z == 1 ? 1u : 0u) << (4 * j + 2);
        bits |= (pm.w == 1 ? 1u : 0u) << (4 * j + 3);
    }
    potbits[f] = (unsigned short)bits;
}

// ---------------------------------------------------------------------------
// Phase A: block (s,p) histograms slice s's edges for v-range p into LDS,
// writes ushort row H[s][vbase..vbase+BINS). No global atomics.
__global__ __launch_bounds__(1024)
void kA_hist(const int* __restrict__ edge_v,
             unsigned short* __restrict__ H) {
    int s = blockIdx.x / PARTS;
    int p = blockIdx.x % PARTS;
    __shared__ int hist[BINS];
    for (int j = threadIdx.x; j < BINS; j += blockDim.x) hist[j] = 0;
    __syncthreads();
    int vbase = p * BINS;
    int ebase = s * SLICE_E;
    for (int i = threadIdx.x; i < SLICE_E; i += blockDim.x) {
        int v = edge_v[ebase + i] - vbase;
        if ((unsigned)v < (unsigned)BINS) atomicAdd(&hist[v], 1);
    }
    __syncthreads();
    unsigned short* row = H + (size_t)s * V_ + vbase;
    for (int j = threadIdx.x; j < BINS; j += blockDim.x)
        row[j] = (unsigned short)hist[j];
}

// ---------------------------------------------------------------------------
// Phase B1: per-block sums of count[v] = sum_s H[s][v]
__global__ void kB_blocksum(const unsigned short* __restrict__ H,
                            int* __restrict__ sums) {
    __shared__ int sm[SCAN_B];
    int tid = threadIdx.x;
    int v = blockIdx.x * SCAN_B + tid;
    int c = 0;
    if (v < V_) {
#pragma unroll
        for (int s = 0; s < SLICES; ++s) c += H[(size_t)s * V_ + v];
    }
    sm[tid] = c;
    __syncthreads();
    for (int r = SCAN_B / 2; r > 0; r >>= 1) {
        if (tid < r) sm[tid] += sm[tid + r];
        __syncthreads();
    }
    if (tid == 0) sums[blockIdx.x] = sm[0];
}

// Phase B2: exclusive scan of block sums (single block); also offs[V]=E.
__global__ void kB_top(const int* __restrict__ sums,
                       int* __restrict__ pre,
                       int* __restrict__ offs) {
    __shared__ int sm[256];
    int tid = threadIdx.x;
    int v = (tid < NB_SCAN) ? sums[tid] : 0;
    sm[tid] = v;
    __syncthreads();
    for (int off = 1; off < 256; off <<= 1) {
        int t = (tid >= off) ? sm[tid - off] : 0;
        __syncthreads();
        sm[tid] += t;
        __syncthreads();
    }
    if (tid < NB_SCAN) pre[tid] = sm[tid] - v;
    if (tid == 0) offs[V_] = E_;
}

// Phase B3: offs[v] = global exclusive prefix; rewrite H[s][v] in place as the
// per-slice RELATIVE base (sum of H[s'][v] for s'<s; fits ushort).
__global__ void kB_offsets(unsigned short* __restrict__ H,
                           const int* __restrict__ pre,
                           int* __restrict__ offs) {
    __shared__ int sm[SCAN_B];
    int tid = threadIdx.x;
    int v = blockIdx.x * SCAN_B + tid;
    int c = 0;
    if (v < V_) {
        int rel = 0;
#pragma unroll
        for (int s = 0; s < SLICES; ++s) {
            size_t ix = (size_t)s * V_ + v;
            int t = H[ix];
            H[ix] = (unsigned short)rel;
            rel += t;
        }
        c = rel;
    }
    sm[tid] = c;
    __syncthreads();
    for (int off = 1; off < SCAN_B; off <<= 1) {
        int t = (tid >= off) ? sm[tid - off] : 0;
        __syncthreads();
        sm[tid] += t;
        __syncthreads();
    }
    if (v < V_) offs[v] = pre[blockIdx.x] + sm[tid] - c;
}

// ---------------------------------------------------------------------------
// Phase C: block (s,p) assigns ranks via LDS running indices (no global
// atomics) and scatters msgs (half2) into the variable-major srt. Scattered
// writes land in a ~250KB partition-local window -> L2-resident.
__global__ __launch_bounds__(1024)
void kC_scatter(const int* __restrict__ edge_v,
                const unsigned short* __restrict__ H,
                const int* __restrict__ offs,
                const float2* __restrict__ msgs,
                __half2* __restrict__ srt,
                int* __restrict__ rank) {
    int s = blockIdx.x / PARTS;
    int p = blockIdx.x % PARTS;
    __shared__ int idx[BINS];
    int vbase = p * BINS;
    const unsigned short* row = H + (size_t)s * V_ + vbase;
    const int* orow = offs + vbase;
    for (int j = threadIdx.x; j < BINS; j += blockDim.x)
        idx[j] = orow[j] + row[j];
    __syncthreads();
    int ebase = s * SLICE_E;
    for (int i = threadIdx.x; i < SLICE_E; i += blockDim.x) {
        int e = ebase + i;
        int v = edge_v[e] - vbase;
        if ((unsigned)v < (unsigned)BINS) {
            int r = atomicAdd(&idx[v], 1);
            float2 m = msgs[e];
            srt[r] = __floats2half2_rn(m.x, m.y);
            rank[e] = r;
        }
    }
}

// ---------------------------------------------------------------------------
// Segment sum over variable-major srt (half2) -> clamped beliefs (f32)
__global__ void k_vb_seg(const int* __restrict__ offs,
                         const __half2* __restrict__ srt,
                         const unsigned char* __restrict__ vb_mask,
                         float2* __restrict__ vb) {
    int v = blockIdx.x * blockDim.x + threadIdx.x;
    if (v >= V_) return;
    int o = offs[v], hi = offs[v + 1];
    float s0 = 0.f, s1 = 0.f;
    for (int i = o; i < hi; ++i) {
        float2 m = __half22float2(srt[i]);
        s0 += m.x; s1 += m.y;
    }
    float b0 = fmaxf(vb_mask[2 * v + 0] ? LN_ZERO : s0, LN_ZERO);
    float b1 = fmaxf(vb_mask[2 * v + 1] ? LN_ZERO : s1, LN_ZERO);
    vb[v] = make_float2(b0, b1);
}

// ---------------------------------------------------------------------------
// Edge-parallel factor messages: 4 threads per factor (d = e & 3).
__global__ void k_factor_msgs(const float2* __restrict__ msgs,
                              const int* __restrict__ edge_v,
                              const int* __restrict__ rank,
                              const float2* __restrict__ vbP,     // clamped prv
                              const float4* __restrict__ pot4,
                              const unsigned short* __restrict__ potbits,
                              const unsigned short* __restrict__ f2v_mask2,
                              const unsigned short* __restrict__ v2f_mask2,
                              float2* __restrict__ out_f2v,
                              __half2* __restrict__ srt) {
    int e = blockIdx.x * blockDim.x + threadIdx.x;
    if (e >= E_) return;
    int d = e & 3;

    float2 b = vbP[edge_v[e]];
    float2 m = msgs[e];
    unsigned short vm = v2f_mask2[e];
    float wx = fmaxf((vm & 0xff) ? LN_ZERO : (b.x - m.x), LN_ZERO);
    float wy = fmaxf((vm >> 8)   ? LN_ZERO : (b.y - m.y), LN_ZERO);

    float w0x = __shfl(wx, 0, 4), w0y = __shfl(wy, 0, 4);
    float w1x = __shfl(wx, 1, 4), w1y = __shfl(wy, 1, 4);
    float w2x = __shfl(wx, 2, 4), w2y = __shfl(wy, 2, 4);
    float w3x = __shfl(wx, 3, 4), w3y = __shfl(wy, 3, 4);

    // states s = 4d+k: bit0(s)=d>>1, bit1(s)=d&1, bit2(s)=k>>1, bit3(s)=k&1
    float4 p = pot4[e];
    unsigned int pb = potbits[e >> 2] >> (4 * d);
    float A = ((d >> 1) ? w0y : w0x) + ((d & 1) ? w1y : w1x);
    float fb0 = p.x + A + w2x + w3x;
    float fb1 = p.y + A + w2x + w3y;
    float fb2 = p.z + A + w2y + w3x;
    float fb3 = p.w + A + w2y + w3y;
    fb0 = fmaxf((pb & 1u) ? LN_ZERO : fb0, LN_ZERO);
    fb1 = fmaxf((pb & 2u) ? LN_ZERO : fb1, LN_ZERO);
    fb2 = fmaxf((pb & 4u) ? LN_ZERO : fb2, LN_ZERO);
    fb3 = fmaxf((pb & 8u) ? LN_ZERO : fb3, LN_ZERO);

    float mk2_0 = fmaxf(fb0, fb1);
    float mk2_1 = fmaxf(fb2, fb3);
    float mk3_0 = fmaxf(fb0, fb2);
    float mk3_1 = fmaxf(fb1, fb3);
    float mloc  = fmaxf(mk2_0, mk2_1);

#pragma unroll
    for (int off = 1; off < 4; off <<= 1) {
        mk2_0 = fmaxf(mk2_0, __shfl_xor(mk2_0, off, 4));
        mk2_1 = fmaxf(mk2_1, __shfl_xor(mk2_1, off, 4));
        mk3_0 = fmaxf(mk3_0, __shfl_xor(mk3_0, off, 4));
        mk3_1 = fmaxf(mk3_1, __shfl_xor(mk3_1, off, 4));
    }
    float ml0 = __shfl(mloc, 0, 4);
    float ml1 = __shfl(mloc, 1, 4);
    float ml2 = __shfl(mloc, 2, 4);
    float ml3 = __shfl(mloc, 3, 4);

    float mm0, mm1;
    if (d == 0)      { mm0 = fmaxf(ml0, ml1); mm1 = fmaxf(ml2, ml3); }
    else if (d == 1) { mm0 = fmaxf(ml0, ml2); mm1 = fmaxf(ml1, ml3); }
    else if (d == 2) { mm0 = mk2_0;           mm1 = mk2_1; }
    else             { mm0 = mk3_0;           mm1 = mk3_1; }

    float raw0 = mm0 - wx;
    float raw1 = mm1 - wy;
    float mx = fmaxf(raw0, raw1);
    float lse = mx + logf(expf(raw0 - mx) + expf(raw1 - mx));
    unsigned short fm = f2v_mask2[e];
    float o0 = fmaxf((fm & 0xff) ? LN_ZERO : (raw0 - lse), LN_ZERO);
    float o1 = fmaxf((fm >> 8)   ? LN_ZERO : (raw1 - lse), LN_ZERO);
    out_f2v[e] = make_float2(o0, o1);
    srt[rank[e]] = __floats2half2_rn(o0, o1);
}

// ---------------------------------------------------------------------------
// Edge-parallel factor beliefs: each thread writes one float4 of [F,16].
__global__ void k_factor_beliefs(const float2* __restrict__ new_f2v,
                                 const float2* __restrict__ vb,      // clamped new
                                 const int* __restrict__ edge_v,
                                 const float4* __restrict__ pot4,
                                 const unsigned short* __restrict__ potbits,
                                 const unsigned short* __restrict__ v2f_mask2,
                                 float4* __restrict__ out_fb4) {
    int e = blockIdx.x * blockDim.x + threadIdx.x;
    if (e >= E_) return;
    int d = e & 3;

    float2 b = vb[edge_v[e]];
    float2 g = new_f2v[e];
    unsigned short vm = v2f_mask2[e];
    float wx = fmaxf((vm & 0xff) ? LN_ZERO : (b.x - g.x), LN_ZERO);
    float wy = fmaxf((vm >> 8)   ? LN_ZERO : (b.y - g.y), LN_ZERO);

    float w0x = __shfl(wx, 0, 4), w0y = __shfl(wy, 0, 4);
    float w1x = __shfl(wx, 1, 4), w1y = __shfl(wy, 1, 4);
    float w2x = __shfl(wx, 2, 4), w2y = __shfl(wy, 2, 4);
    float w3x = __shfl(wx, 3, 4), w3y = __shfl(wy, 3, 4);

    float4 p = pot4[e];
    unsigned int pb = potbits[e >> 2] >> (4 * d);
    float A = ((d >> 1) ? w0y : w0x) + ((d & 1) ? w1y : w1x);
    float o0 = fmaxf((pb & 1u) ? LN_ZERO : (p.x + A + w2x + w3x), LN_ZERO);
    float o1 = fmaxf((pb & 2u) ? LN_ZERO : (p.y + A + w2x + w3y), LN_ZERO);
    float o2 = fmaxf((pb & 4u) ? LN_ZERO : (p.z + A + w2y + w3x), LN_ZERO);
    float o3 = fmaxf((pb & 8u) ? LN_ZERO : (p.w + A + w2y + w3y), LN_ZERO);
    out_fb4[e] = make_float4(o0, o1, o2, o3);
}

// ---------------------------------------------------------------------------
extern "C" void kernel_launch(void* const* d_in, const int* in_sizes, int n_in,
                              void* d_out, int out_size, void* d_ws, size_t ws_size,
                              hipStream_t stream) {
    const float* msgs     = (const float*)d_in[0];           // [E, C]
    const float* pot      = (const float*)d_in[1];           // [F, 16]
    const int*   edge_idx = (const int*)d_in[2];             // [2, E]
    const int*   pot_mask = (const int*)d_in[5];             // [F, 16] int32
    const unsigned char* f2v_mask = (const unsigned char*)d_in[6];  // [E, C]
    const unsigned char* v2f_mask = (const unsigned char*)d_in[7];  // [E, C]
    const unsigned char* vb_mask  = (const unsigned char*)d_in[8];  // [V, C]

    const int* edge_v = edge_idx + E_;

    float* out      = (float*)d_out;
    float* out_f2v  = out;                          // E*C floats
    float* out_vb   = out + (size_t)E_ * 2;         // V*C floats (also vb_prv tmp)
    float* out_fb   = out_vb + (size_t)V_ * 2;      // F*16 floats

    // workspace layout (int units):
    //   H       ushort[SLICES*V] = 1,000,000 ints
    //   offs    int[V+1]         =   250,001
    //   rank    int[E]           = 1,000,000
    //   srt     half2[E]         = 1,000,000
    //   potbits ushort[F]        =   125,000
    //   sums/pre                 =       512
    // total = 3,375,513 ints ~= 13.5 MB
    int* ws_i = (int*)d_ws;
    unsigned short* H = (unsigned short*)ws_i;                 // 1,000,000 ints
    int* offs = ws_i + 1000000;                                // 250,001
    int* rank = offs + 250001;                                 // 1,000,000
    __half2* srt = (__half2*)(rank + E_);                      // 1,000,000 ints
    unsigned short* potbits = (unsigned short*)((int*)srt + E_);  // 125,000 ints
    int* sums = (int*)potbits + F_ / 2;                        // 256
    int* pre  = sums + 256;                                    // 256

    const int B = 256;
    dim3 gE((E_ + B - 1) / B), gF((F_ + B - 1) / B), gV((V_ + B - 1) / B);

    k_prep<<<gF, B, 0, stream>>>((const int4*)pot_mask, potbits);

    // CSR build: LDS-privatized counting sort, no global atomics
    kA_hist<<<SLICES * PARTS, 1024, 0, stream>>>(edge_v, H);
    kB_blocksum<<<NB_SCAN, SCAN_B, 0, stream>>>(H, sums);
    kB_top<<<1, 256, 0, stream>>>(sums, pre, offs);
    kB_offsets<<<NB_SCAN, SCAN_B, 0, stream>>>(H, pre, offs);
    kC_scatter<<<SLICES * PARTS, 1024, 0, stream>>>(edge_v, H, offs,
                                                    (const float2*)msgs, srt, rank);

    // phase 1: vb_prv (into out_vb as temp)
    k_vb_seg<<<gV, B, 0, stream>>>(offs, srt, vb_mask, (float2*)out_vb);

    // factor messages (edge-parallel, fused v2f + scatter of new_f2v into srt)
    k_factor_msgs<<<gE, B, 0, stream>>>((const float2*)msgs, edge_v, rank,
                                        (const float2*)out_vb,
                                        (const float4*)pot, potbits,
                                        (const unsigned short*)f2v_mask,
                                        (const unsigned short*)v2f_mask,
                                        (float2*)out_f2v, srt);

    // phase 2: vb_new (overwrites out_vb) and factor beliefs
    k_vb_seg<<<gV, B, 0, stream>>>(offs, srt, vb_mask, (float2*)out_vb);
    k_factor_beliefs<<<gE, B, 0, stream>>>((const float2*)out_f2v, (const float2*)out_vb,
                                           edge_v, (const float4*)pot, potbits,
                                           (const unsigned short*)v2f_mask,
                                           (float4*)out_fb);
}

// Round 7
// 134.929 us; speedup vs baseline: 1.4240x; 1.4240x over previous
//
#include <hip/hip_runtime.h>
#include <hip/hip_fp16.h>
#include <math.h>

#define LN_ZERO (-100000000000.0f)

constexpr int F_ = 250000;
constexpr int V_ = 250000;
constexpr int E_ = 1000000;      // F_ * 4

// ---------------------------------------------------------------------------
// Prep: compress potmask [F,16] int32 -> ushort bitmask per factor.
__global__ void k_prep(const int4* __restrict__ potmask4,
                       unsigned short* __restrict__ potbits) {
    int f = blockIdx.x * blockDim.x + threadIdx.x;
    if (f >= F_) return;
    unsigned int bits = 0;
#pragma unroll
    for (int j = 0; j < 4; ++j) {
        int4 pm = potmask4[4 * f + j];
        bits |= (pm.x == 1 ? 1u : 0u) << (4 * j + 0);
        bits |= (pm.y == 1 ? 1u : 0u) << (4 * j + 1);
        bits |= (pm.z == 1 ? 1u : 0u) << (4 * j + 2);
        bits |= (pm.w == 1 ? 1u : 0u) << (4 * j + 3);
    }
    potbits[f] = (unsigned short)bits;
}

// ---------------------------------------------------------------------------
// Phase 1 accumulation: acc_prv[v] += msgs[e] via packed-f16 HW atomic.
__global__ void k_accum(const float2* __restrict__ msgs,
                        const int* __restrict__ edge_v,
                        __half2* __restrict__ acc) {
    int e = blockIdx.x * blockDim.x + threadIdx.x;
    if (e >= E_) return;
    float2 m = msgs[e];
    unsafeAtomicAdd(&acc[edge_v[e]], __floats2half2_rn(m.x, m.y));
}

// ---------------------------------------------------------------------------
// Edge-parallel factor messages: 4 threads per factor (d = e & 3).
// Gathers unclamped acc_prv (L2-resident 1MB) + vb_mask, clamps inline,
// computes max-marginal messages, writes out_f2v, and accumulates vb_new
// via packed-f16 atomic into acc_new.
__global__ void k_factor_msgs(const float2* __restrict__ msgs,
                              const int* __restrict__ edge_v,
                              const __half2* __restrict__ accP,
                              const unsigned short* __restrict__ vb_mask2,
                              const float4* __restrict__ pot4,
                              const unsigned short* __restrict__ potbits,
                              const unsigned short* __restrict__ f2v_mask2,
                              const unsigned short* __restrict__ v2f_mask2,
                              float2* __restrict__ out_f2v,
                              __half2* __restrict__ accN) {
    int e = blockIdx.x * blockDim.x + threadIdx.x;
    if (e >= E_) return;
    int d = e & 3;
    int v = edge_v[e];

    // clamped vb_prv for this edge's variable
    float2 s = __half22float2(accP[v]);
    unsigned short vbm = vb_mask2[v];
    float b0 = fmaxf((vbm & 0xff) ? LN_ZERO : s.x, LN_ZERO);
    float b1 = fmaxf((vbm >> 8)   ? LN_ZERO : s.y, LN_ZERO);

    float2 m = msgs[e];
    unsigned short vm = v2f_mask2[e];
    float wx = fmaxf((vm & 0xff) ? LN_ZERO : (b0 - m.x), LN_ZERO);
    float wy = fmaxf((vm >> 8)   ? LN_ZERO : (b1 - m.y), LN_ZERO);

    // all four edges' v2f within the 4-lane group
    float w0x = __shfl(wx, 0, 4), w0y = __shfl(wy, 0, 4);
    float w1x = __shfl(wx, 1, 4), w1y = __shfl(wy, 1, 4);
    float w2x = __shfl(wx, 2, 4), w2y = __shfl(wy, 2, 4);
    float w3x = __shfl(wx, 3, 4), w3y = __shfl(wy, 3, 4);

    // states s = 4d+k: bit0(s)=d>>1, bit1(s)=d&1, bit2(s)=k>>1, bit3(s)=k&1
    float4 p = pot4[e];
    unsigned int pb = potbits[e >> 2] >> (4 * d);
    float A = ((d >> 1) ? w0y : w0x) + ((d & 1) ? w1y : w1x);
    float fb0 = p.x + A + w2x + w3x;
    float fb1 = p.y + A + w2x + w3y;
    float fb2 = p.z + A + w2y + w3x;
    float fb3 = p.w + A + w2y + w3y;
    fb0 = fmaxf((pb & 1u) ? LN_ZERO : fb0, LN_ZERO);
    fb1 = fmaxf((pb & 2u) ? LN_ZERO : fb1, LN_ZERO);
    fb2 = fmaxf((pb & 4u) ? LN_ZERO : fb2, LN_ZERO);
    fb3 = fmaxf((pb & 8u) ? LN_ZERO : fb3, LN_ZERO);

    // per-thread partials split by k-bits, plus local total max
    float mk2_0 = fmaxf(fb0, fb1);   // bit2 == 0
    float mk2_1 = fmaxf(fb2, fb3);   // bit2 == 1
    float mk3_0 = fmaxf(fb0, fb2);   // bit3 == 0
    float mk3_1 = fmaxf(fb1, fb3);   // bit3 == 1
    float mloc  = fmaxf(mk2_0, mk2_1);

#pragma unroll
    for (int off = 1; off < 4; off <<= 1) {
        mk2_0 = fmaxf(mk2_0, __shfl_xor(mk2_0, off, 4));
        mk2_1 = fmaxf(mk2_1, __shfl_xor(mk2_1, off, 4));
        mk3_0 = fmaxf(mk3_0, __shfl_xor(mk3_0, off, 4));
        mk3_1 = fmaxf(mk3_1, __shfl_xor(mk3_1, off, 4));
    }
    float ml0 = __shfl(mloc, 0, 4);
    float ml1 = __shfl(mloc, 1, 4);
    float ml2 = __shfl(mloc, 2, 4);
    float ml3 = __shfl(mloc, 3, 4);

    float mm0, mm1;
    if (d == 0)      { mm0 = fmaxf(ml0, ml1); mm1 = fmaxf(ml2, ml3); }
    else if (d == 1) { mm0 = fmaxf(ml0, ml2); mm1 = fmaxf(ml1, ml3); }
    else if (d == 2) { mm0 = mk2_0;           mm1 = mk2_1; }
    else             { mm0 = mk3_0;           mm1 = mk3_1; }

    float raw0 = mm0 - wx;
    float raw1 = mm1 - wy;
    float mx = fmaxf(raw0, raw1);
    float lse = mx + logf(expf(raw0 - mx) + expf(raw1 - mx));
    unsigned short fm = f2v_mask2[e];
    float o0 = fmaxf((fm & 0xff) ? LN_ZERO : (raw0 - lse), LN_ZERO);
    float o1 = fmaxf((fm >> 8)   ? LN_ZERO : (raw1 - lse), LN_ZERO);
    out_f2v[e] = make_float2(o0, o1);
    unsafeAtomicAdd(&accN[v], __floats2half2_rn(o0, o1));
}

// ---------------------------------------------------------------------------
// Finalize vb_new: clamp acc_new -> out_vb (f32 output)
__global__ void k_fin_vb(const __half2* __restrict__ accN,
                         const unsigned short* __restrict__ vb_mask2,
                         float2* __restrict__ out_vb) {
    int v = blockIdx.x * blockDim.x + threadIdx.x;
    if (v >= V_) return;
    float2 s = __half22float2(accN[v]);
    unsigned short vbm = vb_mask2[v];
    float b0 = fmaxf((vbm & 0xff) ? LN_ZERO : s.x, LN_ZERO);
    float b1 = fmaxf((vbm >> 8)   ? LN_ZERO : s.y, LN_ZERO);
    out_vb[v] = make_float2(b0, b1);
}

// ---------------------------------------------------------------------------
// Edge-parallel factor beliefs: each thread writes one float4 of [F,16].
__global__ void k_factor_beliefs(const float2* __restrict__ new_f2v,
                                 const float2* __restrict__ vb,      // clamped new
                                 const int* __restrict__ edge_v,
                                 const float4* __restrict__ pot4,
                                 const unsigned short* __restrict__ potbits,
                                 const unsigned short* __restrict__ v2f_mask2,
                                 float4* __restrict__ out_fb4) {
    int e = blockIdx.x * blockDim.x + threadIdx.x;
    if (e >= E_) return;
    int d = e & 3;

    float2 b = vb[edge_v[e]];
    float2 g = new_f2v[e];
    unsigned short vm = v2f_mask2[e];
    float wx = fmaxf((vm & 0xff) ? LN_ZERO : (b.x - g.x), LN_ZERO);
    float wy = fmaxf((vm >> 8)   ? LN_ZERO : (b.y - g.y), LN_ZERO);

    float w0x = __shfl(wx, 0, 4), w0y = __shfl(wy, 0, 4);
    float w1x = __shfl(wx, 1, 4), w1y = __shfl(wy, 1, 4);
    float w2x = __shfl(wx, 2, 4), w2y = __shfl(wy, 2, 4);
    float w3x = __shfl(wx, 3, 4), w3y = __shfl(wy, 3, 4);

    float4 p = pot4[e];
    unsigned int pb = potbits[e >> 2] >> (4 * d);
    float A = ((d >> 1) ? w0y : w0x) + ((d & 1) ? w1y : w1x);
    float o0 = fmaxf((pb & 1u) ? LN_ZERO : (p.x + A + w2x + w3x), LN_ZERO);
    float o1 = fmaxf((pb & 2u) ? LN_ZERO : (p.y + A + w2x + w3y), LN_ZERO);
    float o2 = fmaxf((pb & 4u) ? LN_ZERO : (p.z + A + w2y + w3x), LN_ZERO);
    float o3 = fmaxf((pb & 8u) ? LN_ZERO : (p.w + A + w2y + w3y), LN_ZERO);
    out_fb4[e] = make_float4(o0, o1, o2, o3);
}

// ---------------------------------------------------------------------------
extern "C" void kernel_launch(void* const* d_in, const int* in_sizes, int n_in,
                              void* d_out, int out_size, void* d_ws, size_t ws_size,
                              hipStream_t stream) {
    const float* msgs     = (const float*)d_in[0];           // [E, C]
    const float* pot      = (const float*)d_in[1];           // [F, 16]
    const int*   edge_idx = (const int*)d_in[2];             // [2, E]
    const int*   pot_mask = (const int*)d_in[5];             // [F, 16] int32
    const unsigned char* f2v_mask = (const unsigned char*)d_in[6];  // [E, C]
    const unsigned char* v2f_mask = (const unsigned char*)d_in[7];  // [E, C]
    const unsigned char* vb_mask  = (const unsigned char*)d_in[8];  // [V, C]

    const int* edge_v = edge_idx + E_;

    float* out      = (float*)d_out;
    float* out_f2v  = out;                          // E*C floats
    float* out_vb   = out + (size_t)E_ * 2;         // V*C floats
    float* out_fb   = out_vb + (size_t)V_ * 2;      // F*16 floats

    // workspace: accP[V] half2 + accN[V] half2 (contiguous, zeroed together),
    // potbits ushort[F]  -> ~2.5 MB total
    __half2* accP = (__half2*)d_ws;                 // V half2 = 1 MB
    __half2* accN = accP + V_;                      // V half2 = 1 MB
    unsigned short* potbits = (unsigned short*)(accN + V_);   // 0.5 MB

    hipMemsetAsync(accP, 0, 2 * (size_t)V_ * sizeof(__half2), stream);

    const int B = 256;
    dim3 gE((E_ + B - 1) / B), gF((F_ + B - 1) / B), gV((V_ + B - 1) / B);

    k_prep<<<gF, B, 0, stream>>>((const int4*)pot_mask, potbits);

    // phase 1: vb_prv accumulation via packed-f16 atomics
    k_accum<<<gE, B, 0, stream>>>((const float2*)msgs, edge_v, accP);

    // factor messages (clamps vb_prv inline; fuses vb_new accumulation)
    k_factor_msgs<<<gE, B, 0, stream>>>((const float2*)msgs, edge_v, accP,
                                        (const unsigned short*)vb_mask,
                                        (const float4*)pot, potbits,
                                        (const unsigned short*)f2v_mask,
                                        (const unsigned short*)v2f_mask,
                                        (float2*)out_f2v, accN);

    // phase 2: finalize vb_new, then factor beliefs
    k_fin_vb<<<gV, B, 0, stream>>>(accN, (const unsigned short*)vb_mask,
                                   (float2*)out_vb);
    k_factor_beliefs<<<gE, B, 0, stream>>>((const float2*)out_f2v, (const float2*)out_vb,
                                           edge_v, (const float4*)pot, potbits,
                                           (const unsigned short*)v2f_mask,
                                           (float4*)out_fb);
}